// Round 8
// baseline (232.519 us; speedup 1.0000x reference)
//
#include <hip/hip_runtime.h>
#include <math.h>

#define BATCH_N   32768
#define IN_F      784
#define HID_F     256
#define NCLS      10
#define BM        64          // batch rows per block
#define BK        32          // K per MFMA step
#define NKT       25          // ceil(784/32); kt=24 partial (peeled)
#define NTHREADS  512         // 8 waves: wave (rg,cg) = rows rg*32+[0,32) x cols cg*64+[0,64)

typedef __attribute__((ext_vector_type(8))) short short8;  // 8 bf16 = one MFMA operand frag
typedef __attribute__((ext_vector_type(4))) float f32x4;

// d_ws: w1 pre-converted split-bf16 frag images (unchanged layout):
//   slot s = (kt*16 + ct)*64 + lane; byte off = kt*16384 + ct*1024 + lane*16
#define WS_W1H 0
#define WS_W1L 409600          // 25*16*64*16

union S8U { short8 s; uint4 u; };

// fp32x8 -> split bf16 (hi = truncate, lo = exact residual truncated)
__device__ __forceinline__ void cvt8(float4 a, float4 b, short8* hi, short8* lo) {
    const unsigned M = 0xFFFF0000u;
    const unsigned ux = __float_as_uint(a.x), uy = __float_as_uint(a.y),
                   uz = __float_as_uint(a.z), uw = __float_as_uint(a.w),
                   vx = __float_as_uint(b.x), vy = __float_as_uint(b.y),
                   vz = __float_as_uint(b.z), vw = __float_as_uint(b.w);
    S8U h, l;
    h.u.x = (ux >> 16) | (uy & M);
    h.u.y = (uz >> 16) | (uw & M);
    h.u.z = (vx >> 16) | (vy & M);
    h.u.w = (vz >> 16) | (vw & M);
    const float rx = a.x - __uint_as_float(ux & M);
    const float ry = a.y - __uint_as_float(uy & M);
    const float rz = a.z - __uint_as_float(uz & M);
    const float rw = a.w - __uint_as_float(uw & M);
    const float sx = b.x - __uint_as_float(vx & M);
    const float sy = b.y - __uint_as_float(vy & M);
    const float sz = b.z - __uint_as_float(vz & M);
    const float sw_ = b.w - __uint_as_float(vw & M);
    l.u.x = (__float_as_uint(rx) >> 16) | (__float_as_uint(ry) & M);
    l.u.y = (__float_as_uint(rz) >> 16) | (__float_as_uint(rw) & M);
    l.u.z = (__float_as_uint(sx) >> 16) | (__float_as_uint(sy) & M);
    l.u.w = (__float_as_uint(sz) >> 16) | (__float_as_uint(sw_) & M);
    *hi = h.s; *lo = l.s;
}

// ---- pre-pass: w1 -> split-bf16 frag images in d_ws (unchanged) ----
__global__ __launch_bounds__(256)
void prep_w1_kernel(const float* __restrict__ w1, char* __restrict__ ws) {
    const int s    = blockIdx.x * 256 + threadIdx.x;   // 25600 slots
    const int lane = s & 63, ct = (s >> 6) & 15, kt = s >> 10;
    const int n    = ct * 16 + (lane & 15);
    const int k0   = kt * 32 + (lane >> 4) * 8;
    float4 a = make_float4(0.f, 0.f, 0.f, 0.f), b = a;
    if (k0 + 7 < IN_F) {
        const float* p = w1 + (size_t)n * IN_F + k0;
        a = *(const float4*)p;
        b = *(const float4*)(p + 4);
    }
    short8 hi, lo;
    cvt8(a, b, &hi, &lo);
    *(short8*)(ws + WS_W1H + (size_t)s * 16) = hi;
    *(short8*)(ws + WS_W1L + (size_t)s * 16) = lo;
}

// ---- main: 8-wave blocks, 10 KB LDS, register-resident layer 2 ----
__global__ __launch_bounds__(NTHREADS, 4)   // 4 waves/EU -> 2 blocks/CU, VGPR<=128
void mlp_mfma_kernel(const float* __restrict__ x,
                     const char*  __restrict__ wsb,
                     const float* __restrict__ b1,
                     const float* __restrict__ w2,
                     const float* __restrict__ b2,
                     float* __restrict__ out)
{
    __shared__ float part[4][BM][NCLS + 2];  // partial logits, pad 10->12 (12 KB)

    const int tid  = threadIdx.x;
    const int w    = tid >> 6;          // wave 0..7
    const int rg   = w >> 2;            // row group: rows rg*32 + [0,32)
    const int cg   = w & 3;             // col group: ct_global = cg*4 + c
    const int lane = tid & 63;
    const int m    = lane & 15;
    const int quad = lane >> 4;
    const int kq   = quad * 8;
    const int row0 = blockIdx.x * BM;

    f32x4 acc[2][4];                    // [rt][ct] 16x16 tiles
    #pragma unroll
    for (int a = 0; a < 2; ++a)
        #pragma unroll
        for (int b = 0; b < 4; ++b)
            acc[a][b] = (f32x4){0.f, 0.f, 0.f, 0.f};

    // A: rows row0 + rg*32 + rt*16 + m
    const float* xb[2];
    #pragma unroll
    for (int rt = 0; rt < 2; ++rt)
        xb[rt] = x + (size_t)(row0 + rg * 32 + rt * 16 + m) * IN_F;

    const char* bhp = wsb + WS_W1H + ((size_t)(cg * 4) * 64 + lane) * 16;
    const char* blp = wsb + WS_W1L + ((size_t)(cg * 4) * 64 + lane) * 16;

    #pragma unroll 4
    for (int kt = 0; kt < NKT - 1; ++kt) {          // kt = 0..23, branch-free
        const int kb = kt * BK;
        short8 bh[4], bl[4];
        #pragma unroll
        for (int c = 0; c < 4; ++c) {
            bh[c] = *(const short8*)(bhp + (size_t)kt * 16384 + c * 1024);
            bl[c] = *(const short8*)(blp + (size_t)kt * 16384 + c * 1024);
        }
        short8 ah[2], al[2];
        #pragma unroll
        for (int rt = 0; rt < 2; ++rt) {
            const float4 a0 = *(const float4*)(xb[rt] + kb + kq);
            const float4 a1 = *(const float4*)(xb[rt] + kb + kq + 4);
            cvt8(a0, a1, &ah[rt], &al[rt]);
        }
        #pragma unroll
        for (int rt = 0; rt < 2; ++rt)
            #pragma unroll
            for (int c = 0; c < 4; ++c) {
                acc[rt][c] = __builtin_amdgcn_mfma_f32_16x16x32_bf16(ah[rt], bh[c], acc[rt][c], 0, 0, 0);
                acc[rt][c] = __builtin_amdgcn_mfma_f32_16x16x32_bf16(al[rt], bh[c], acc[rt][c], 0, 0, 0);
                acc[rt][c] = __builtin_amdgcn_mfma_f32_16x16x32_bf16(ah[rt], bl[c], acc[rt][c], 0, 0, 0);
            }
    }

    // ---- peeled tail kt=24: k in [768,784); quads 2,3 are pad -> zero ----
    {
        const int kt = NKT - 1;
        short8 bh[4], bl[4];
        #pragma unroll
        for (int c = 0; c < 4; ++c) {
            bh[c] = *(const short8*)(bhp + (size_t)kt * 16384 + c * 1024);
            bl[c] = *(const short8*)(blp + (size_t)kt * 16384 + c * 1024);
        }
        const int kon = (768 + kq) > (IN_F - 8) ? (IN_F - 8) : (768 + kq);
        short8 ah[2], al[2];
        #pragma unroll
        for (int rt = 0; rt < 2; ++rt) {
            const float4 a0 = *(const float4*)(xb[rt] + kon);
            const float4 a1 = *(const float4*)(xb[rt] + kon + 4);
            cvt8(a0, a1, &ah[rt], &al[rt]);
        }
        if (quad >= 2) {
            const short8 zz = {0, 0, 0, 0, 0, 0, 0, 0};
            #pragma unroll
            for (int rt = 0; rt < 2; ++rt) { ah[rt] = zz; al[rt] = zz; }
        }
        #pragma unroll
        for (int rt = 0; rt < 2; ++rt)
            #pragma unroll
            for (int c = 0; c < 4; ++c) {
                acc[rt][c] = __builtin_amdgcn_mfma_f32_16x16x32_bf16(ah[rt], bh[c], acc[rt][c], 0, 0, 0);
                acc[rt][c] = __builtin_amdgcn_mfma_f32_16x16x32_bf16(al[rt], bh[c], acc[rt][c], 0, 0, 0);
                acc[rt][c] = __builtin_amdgcn_mfma_f32_16x16x32_bf16(ah[rt], bl[c], acc[rt][c], 0, 0, 0);
            }
    }

    // ---- layer 2 from registers ----
    // lane holds h[row][col] for col=(cg*4+ct)*16+m, row=rg*32+rt*16+quad*4+reg
    // (C/D layout: col=lane&15 within tile, row=quad*4+reg — m89-verified)
    float w2v[4][NCLS], b1v[4];
    #pragma unroll
    for (int ct = 0; ct < 4; ++ct) {
        const int col = (cg * 4 + ct) * 16 + m;
        b1v[ct] = b1[col];
        #pragma unroll
        for (int c = 0; c < NCLS; ++c)
            w2v[ct][c] = w2[c * HID_F + col];   // 2.5 KB slice, L1-hot
    }
    #pragma unroll
    for (int rt = 0; rt < 2; ++rt) {
        float p[4][NCLS];
        #pragma unroll
        for (int reg = 0; reg < 4; ++reg)
            #pragma unroll
            for (int c = 0; c < NCLS; ++c) p[reg][c] = 0.f;
        #pragma unroll
        for (int ct = 0; ct < 4; ++ct)
            #pragma unroll
            for (int reg = 0; reg < 4; ++reg) {
                const float h = fmaxf(acc[rt][ct][reg] + b1v[ct], 0.f);
                #pragma unroll
                for (int c = 0; c < NCLS; ++c) p[reg][c] += h * w2v[ct][c];
            }
        // reduce over m (lane bits 0..3): all 16 m-lanes share (quad,reg) rows
        #pragma unroll
        for (int reg = 0; reg < 4; ++reg)
            #pragma unroll
            for (int c = 0; c < NCLS; ++c) {
                float v = p[reg][c];
                v += __shfl_xor(v, 1);
                v += __shfl_xor(v, 2);
                v += __shfl_xor(v, 4);
                v += __shfl_xor(v, 8);
                p[reg][c] = v;
            }
        if (m == 0) {
            #pragma unroll
            for (int reg = 0; reg < 4; ++reg) {
                const int row = rg * 32 + rt * 16 + quad * 4 + reg;
                #pragma unroll
                for (int c = 0; c < NCLS; ++c)
                    part[cg][row][c] = p[reg][c];
            }
        }
    }
    __syncthreads();

    // ---- final: reduce 4 col-group partials, softmax, store ----
    if (tid < 4 * BM) {
        const int row = tid >> 2;       // 0..63
        const int cgi = tid & 3;
        float lg[NCLS];
        #pragma unroll
        for (int c = 0; c < NCLS; ++c) lg[c] = part[cgi][row][c];
        #pragma unroll
        for (int c = 0; c < NCLS; ++c) {   // reduce over cgi (lane bits 0,1)
            float v = lg[c];
            v += __shfl_xor(v, 1);
            v += __shfl_xor(v, 2);
            lg[c] = v;
        }
        if (cgi == 0) {
            float mx = -1e30f;
            #pragma unroll
            for (int c = 0; c < NCLS; ++c) { lg[c] += b2[c]; mx = fmaxf(mx, lg[c]); }
            float s = 0.f;
            #pragma unroll
            for (int c = 0; c < NCLS; ++c) { lg[c] = __expf(lg[c] - mx); s += lg[c]; }
            const float inv = 1.f / s;
            float* o = out + (size_t)(row0 + row) * NCLS;
            #pragma unroll
            for (int c = 0; c < NCLS; ++c) o[c] = lg[c] * inv;
        }
    }
}

extern "C" void kernel_launch(void* const* d_in, const int* in_sizes, int n_in,
                              void* d_out, int out_size, void* d_ws, size_t ws_size,
                              hipStream_t stream)
{
    const float* x  = (const float*)d_in[0];
    const float* w1 = (const float*)d_in[1];
    const float* b1 = (const float*)d_in[2];
    const float* w2 = (const float*)d_in[3];
    const float* b2 = (const float*)d_in[4];
    float* out = (float*)d_out;

    hipLaunchKernelGGL(prep_w1_kernel, dim3(100), dim3(256), 0, stream,
                       w1, (char*)d_ws);
    hipLaunchKernelGGL(mlp_mfma_kernel, dim3(BATCH_N / BM), dim3(NTHREADS), 0, stream,
                       x, (const char*)d_ws, b1, w2, b2, out);
}